// Round 1
// baseline (181.459 us; speedup 1.0000x reference)
//
#include <hip/hip_runtime.h>
#include <math.h>

// Problem constants (fixed by reference setup_inputs)
constexpr int B = 32, C = 512, N = 1024;   // N = H*W

typedef float f32x4 __attribute__((ext_vector_type(4)));
typedef _Float16 f16x8 __attribute__((ext_vector_type(8)));
typedef unsigned short u16x4 __attribute__((ext_vector_type(4)));

// fp16 bit helpers
__device__ __forceinline__ unsigned short f32_to_f16u(float v) {
  union { _Float16 h; unsigned short u; } cv; cv.h = (_Float16)v; return cv.u;
}
__device__ __forceinline__ float f16u_to_f32(unsigned short u) {
  union { _Float16 h; unsigned short u; } cv; cv.u = u; return (float)cv.h;
}

// async global->LDS, 16B per lane; LDS dest = wave-uniform base + lane*16
__device__ __forceinline__ void glds16(const void* g, void* l) {
  __builtin_amdgcn_global_load_lds((const __attribute__((address_space(1))) void*)g,
                                   (__attribute__((address_space(3))) void*)l, 16, 0, 0);
}

// ---------------------------------------------------------------------------
// Kernel 0: x (fp32 [B,C,N]) -> fp16 xf [B,C,N] and transposed xfT [B,N,C].
// 64x64 tiles, float4 loads, LDS transpose.  (unchanged — already ~mem-bound)
// ---------------------------------------------------------------------------
__global__ __launch_bounds__(256) void convert_kernel(const float* __restrict__ x,
                                                      unsigned short* __restrict__ xf,
                                                      unsigned short* __restrict__ xfT) {
  const int b = blockIdx.z;
  const int cy = blockIdx.y * 64;   // C tile origin
  const int nx = blockIdx.x * 64;   // N tile origin
  const int t = threadIdx.x;
  const int r = t >> 4, c4 = (t & 15) * 4;

  __shared__ unsigned T[64][65];    // u32 slots: 2-way-max banking both phases

#pragma unroll
  for (int rr = 0; rr < 64; rr += 16) {
    const int row = rr + r;
    const size_t gi = ((size_t)b * C + cy + row) * N + nx + c4;
    const float4 v = *(const float4*)&x[gi];
    u16x4 h;
    h[0] = f32_to_f16u(v.x); h[1] = f32_to_f16u(v.y);
    h[2] = f32_to_f16u(v.z); h[3] = f32_to_f16u(v.w);
    *(u16x4*)&xf[gi] = h;
    T[row][c4 + 0] = h[0]; T[row][c4 + 1] = h[1];
    T[row][c4 + 2] = h[2]; T[row][c4 + 3] = h[3];
  }
  __syncthreads();
#pragma unroll
  for (int rr = 0; rr < 64; rr += 16) {
    const int nrow = rr + r;
    u16x4 o;
    o[0] = (unsigned short)T[c4 + 0][nrow]; o[1] = (unsigned short)T[c4 + 1][nrow];
    o[2] = (unsigned short)T[c4 + 2][nrow]; o[3] = (unsigned short)T[c4 + 3][nrow];
    *(u16x4*)&xfT[((size_t)b * N + nx + nrow) * C + cy + c4] = o;
  }
}

// ---------------------------------------------------------------------------
// Kernel 1 (FULLY FUSED): rows i0..i0+63 of G = F*F^T (fp16 MFMA), in-block
// softmax(rowmin - G) -> fp16 A-tile kept in LDS (64x512, XOR-swizzled),
// then E = A*F via xfT staging, out = beta*E + x — no Af global round-trip,
// no third kernel.  LDS: P dbuf 64 KB + Atile 64 KB = 128 KB, 1 block/CU,
// 1024 threads = 16 waves (4/SIMD).
// ---------------------------------------------------------------------------
__global__ __launch_bounds__(1024, 4) void gram_soft_av(const unsigned short* __restrict__ xf,
                                                        const unsigned short* __restrict__ xfT,
                                                        const float* __restrict__ beta,
                                                        float* __restrict__ out) {
  const int l = blockIdx.x;
  const int xcd = l & 7, seq = l >> 3;     // 32 blocks per XCD
  const int b = xcd + 8 * (seq >> 3);      // 4 batch-groups per XCD (L2 reuse)
  const int i0 = (seq & 7) * 64;           // row-tile origin

  const unsigned short* __restrict__ Fh = xf  + (size_t)b * C * N;
  const unsigned short* __restrict__ FT = xfT + (size_t)b * N * C;
  float* __restrict__ ob = out + (size_t)b * C * N;

  __shared__ __align__(16) unsigned short Pb[2][512 * 32];   // 64 KB staging dbuf
  __shared__ __align__(16) unsigned short Atile[64 * 512];   // 64 KB fp16 A rows

  const int t = threadIdx.x, wave = t >> 6, lane = t & 63;
  const int wi = wave >> 3;                // 0..1: 32-row half
  const int wj = wave & 7;                 // 0..7: 64-col strip
  const int lrow = lane & 15, quad = lane >> 4;
  const int srow = lane >> 2;                              // row in 16-row chunk
  const int sel  = ((lane & 3) ^ ((lane >> 3) & 3)) * 8;   // swizzled src granule

  f32x4 acc[2][4] = {};   // [ti: 16-row tiles][tj: 16-col tiles]

  // ========================= Phase 1: Gram G = F F^T =========================
#define STAGE(k0, nb)                                                     \
  {                                                                       \
    _Pragma("unroll")                                                     \
    for (int cc = 0; cc < 2; ++cc) {                                      \
      const int chunk = wave * 2 + cc;                                    \
      const int row = chunk * 16 + srow;                                  \
      glds16(Fh + (size_t)row * N + (k0) + sel, &Pb[nb][chunk * 512]);    \
    }                                                                     \
  }

  STAGE(0, 0);

  for (int it = 0; it < 32; ++it) {
    const int k0 = it * 32;
    __syncthreads();                       // buf[it&1] staged; prev readers done
    if (it + 1 < 32) STAGE(k0 + 32, (it + 1) & 1);

    const unsigned short* __restrict__ Pc = Pb[it & 1];
    f16x8 ah[2], bh[4];
#pragma unroll
    for (int ti = 0; ti < 2; ++ti) {
      const int r = i0 + wi * 32 + ti * 16 + lrow;
      ah[ti] = *(const f16x8*)&Pc[r * 32 + (quad ^ ((r >> 1) & 3)) * 8];
    }
#pragma unroll
    for (int tj = 0; tj < 4; ++tj) {
      const int r = wj * 64 + tj * 16 + lrow;
      bh[tj] = *(const f16x8*)&Pc[r * 32 + (quad ^ ((r >> 1) & 3)) * 8];
    }
#pragma unroll
    for (int ti = 0; ti < 2; ++ti)
#pragma unroll
      for (int tj = 0; tj < 4; ++tj)
        acc[ti][tj] = __builtin_amdgcn_mfma_f32_16x16x32_f16(ah[ti], bh[tj], acc[ti][tj], 0, 0, 0);
  }
#undef STAGE

  // ==================== fused softmax (rows complete in block) ===============
  __syncthreads();                    // all MFMA LDS reads done; reuse LDS
  float* red = (float*)&Pb[0][0];     // 16 waves x 32 row-slots
  float* fin = red + 512;             // 64 finals

  // per-lane min over its cols; rows rs = wi*32 + ti*16 + quad*4 + rr
  float m[8];
#pragma unroll
  for (int ti = 0; ti < 2; ++ti)
#pragma unroll
    for (int rr = 0; rr < 4; ++rr)
      m[ti * 4 + rr] = fminf(fminf(acc[ti][0][rr], acc[ti][1][rr]),
                             fminf(acc[ti][2][rr], acc[ti][3][rr]));
#pragma unroll
  for (int o = 1; o < 16; o <<= 1)
#pragma unroll
    for (int s = 0; s < 8; ++s) m[s] = fminf(m[s], __shfl_xor(m[s], o, 64));
  if (lrow == 0)
#pragma unroll
    for (int ti = 0; ti < 2; ++ti)
#pragma unroll
      for (int rr = 0; rr < 4; ++rr)
        red[wave * 32 + ti * 16 + quad * 4 + rr] = m[ti * 4 + rr];
  __syncthreads();
  if (t < 64) {
    const int wig = t >> 5, loc = t & 31;
    float v = red[(wig * 8) * 32 + loc];
#pragma unroll
    for (int j = 1; j < 8; ++j) v = fminf(v, red[(wig * 8 + j) * 32 + loc]);
    fin[t] = v;
  }
  __syncthreads();

  // exponentiate in place, per-lane partial row sums
  float sm[8];
#pragma unroll
  for (int ti = 0; ti < 2; ++ti)
#pragma unroll
    for (int rr = 0; rr < 4; ++rr) {
      const float mn = fin[wi * 32 + ti * 16 + quad * 4 + rr];
      float s = 0.f;
#pragma unroll
      for (int tj = 0; tj < 4; ++tj) {
        const float e = __expf(mn - acc[ti][tj][rr]);
        acc[ti][tj][rr] = e;
        s += e;
      }
      sm[ti * 4 + rr] = s;
    }
#pragma unroll
  for (int o = 1; o < 16; o <<= 1)
#pragma unroll
    for (int s = 0; s < 8; ++s) sm[s] += __shfl_xor(sm[s], o, 64);
  if (lrow == 0)
#pragma unroll
    for (int ti = 0; ti < 2; ++ti)
#pragma unroll
      for (int rr = 0; rr < 4; ++rr)
        red[wave * 32 + ti * 16 + quad * 4 + rr] = sm[ti * 4 + rr];
  __syncthreads();
  if (t < 64) {
    const int wig = t >> 5, loc = t & 31;
    float v = 0.f;
#pragma unroll
    for (int j = 0; j < 8; ++j) v += red[(wig * 8 + j) * 32 + loc];
    fin[t] = 1.0f / v;
  }
  __syncthreads();

  // scale + write fp16 A into LDS Atile, XOR-swizzled: element (r,c) at
  // r*512 + ((c>>3 ^ (r&7))*8 | (c&7)) -> K-major frag reads are 2-way-free.
#pragma unroll
  for (int ti = 0; ti < 2; ++ti)
#pragma unroll
    for (int rr = 0; rr < 4; ++rr) {
      const float inv = fin[wi * 32 + ti * 16 + quad * 4 + rr];
      const int rl = wi * 32 + ti * 16 + quad * 4 + rr;   // local row 0..63
#pragma unroll
      for (int tj = 0; tj < 4; ++tj) {
        const int gcol = wj * 64 + tj * 16 + lrow;
        Atile[rl * 512 + ((((gcol >> 3) ^ (rl & 7)) << 3) | (gcol & 7))] =
            f32_to_f16u(acc[ti][tj][rr] * inv);
      }
    }
  __syncthreads();                    // Atile visible to all waves; red/fin dead

  // ======================= Phase 2: E = A*F, out = beta*E + x ================
  // 2 column-half passes of 512 (B-panel dbuf stays 2x32 KB in Pb).
  const float bv = beta[0];

  for (int jp = 0; jp < 2; ++jp) {
    f32x4 eacc[2][4] = {};
#define STAGE_E(k0, nb)                                                        \
    {                                                                          \
      _Pragma("unroll")                                                        \
      for (int cc = 0; cc < 2; ++cc) {                                         \
        const int chunk = wave * 2 + cc;                                       \
        const int row = chunk * 16 + srow;                                     \
        glds16(FT + (size_t)(jp * 512 + row) * C + (k0) + sel,                 \
               &Pb[nb][chunk * 512]);                                          \
      }                                                                        \
    }
    STAGE_E(0, 0);
    for (int it = 0; it < 16; ++it) {
      const int k0 = it * 32;
      __syncthreads();
      if (it + 1 < 16) STAGE_E(k0 + 32, (it + 1) & 1);

      const unsigned short* __restrict__ Pc = Pb[it & 1];
      f16x8 ah[2], bh[4];
#pragma unroll
      for (int ti = 0; ti < 2; ++ti) {
        const int ra = wi * 32 + ti * 16 + lrow;          // A row 0..63
        ah[ti] = *(const f16x8*)&Atile[ra * 512 + ((((k0 >> 3) | quad) ^ (ra & 7)) << 3)];
      }
#pragma unroll
      for (int tj = 0; tj < 4; ++tj) {
        const int rb = wj * 64 + tj * 16 + lrow;          // F^T row within half
        bh[tj] = *(const f16x8*)&Pc[rb * 32 + ((quad ^ ((rb >> 1) & 3)) << 3)];
      }
#pragma unroll
      for (int ti = 0; ti < 2; ++ti)
#pragma unroll
        for (int tj = 0; tj < 4; ++tj)
          eacc[ti][tj] = __builtin_amdgcn_mfma_f32_16x16x32_f16(ah[ti], bh[tj], eacc[ti][tj], 0, 0, 0);
    }
#undef STAGE_E

    // Epilogue: per-wave LDS transpose of each 16x64 strip -> float4 I/O,
    // residual from fp16 xf (|err| <= |x|*4.9e-4), nontemporal stores.
    __syncthreads();                   // all Pb reads done; reuse as f32 scratch
    float* fs = (float*)&Pb[0][0] + wave * 1024;   // 4 KB per wave
#pragma unroll
    for (int ti = 0; ti < 2; ++ti) {
#pragma unroll
      for (int tj = 0; tj < 4; ++tj)
#pragma unroll
        for (int r = 0; r < 4; ++r)
          fs[(quad * 4 + r) * 64 + tj * 16 + lrow] = eacc[ti][tj][r];
      __syncthreads();
#pragma unroll
      for (int p = 0; p < 4; ++p) {
        const int f = p * 64 + lane;
        const int rr2 = f >> 4, cc4 = (f & 15) * 4;
        const f32x4 e = *(const f32x4*)&fs[rr2 * 64 + cc4];
        const int gr = i0 + wi * 32 + ti * 16 + rr2;
        const int gc = jp * 512 + wj * 64 + cc4;
        const size_t o = (size_t)gr * N + gc;
        const u16x4 xv = *(const u16x4*)&Fh[o];
        f32x4 ov;
        ov[0] = fmaf(bv, e[0], f16u_to_f32(xv[0]));
        ov[1] = fmaf(bv, e[1], f16u_to_f32(xv[1]));
        ov[2] = fmaf(bv, e[2], f16u_to_f32(xv[2]));
        ov[3] = fmaf(bv, e[3], f16u_to_f32(xv[3]));
        __builtin_nontemporal_store(ov, (f32x4*)&ob[o]);
      }
      __syncthreads();
    }
  }
}

// ---------------------------------------------------------------------------
extern "C" void kernel_launch(void* const* d_in, const int* in_sizes, int n_in,
                              void* d_out, int out_size, void* d_ws, size_t ws_size,
                              hipStream_t stream) {
  const float* x    = (const float*)d_in[0];
  const float* beta = (const float*)d_in[1];
  float* out = (float*)d_out;

  char* ws = (char*)d_ws;
  unsigned short* xf  = (unsigned short*)ws; ws += (size_t)B * C * N * 2;  // 32 MB
  unsigned short* xfT = (unsigned short*)ws;                               // 32 MB

  convert_kernel<<<dim3(N / 64, C / 64, B), dim3(256),  0, stream>>>(x, xf, xfT);
  gram_soft_av  <<<dim3(256),               dim3(1024), 0, stream>>>(xf, xfT, beta, out);
}

// Round 2
// 177.397 us; speedup vs baseline: 1.0229x; 1.0229x over previous
//
#include <hip/hip_runtime.h>
#include <math.h>

// Problem constants (fixed by reference setup_inputs)
constexpr int B = 32, C = 512, N = 1024;   // N = H*W

typedef float f32x4 __attribute__((ext_vector_type(4)));
typedef _Float16 f16x8 __attribute__((ext_vector_type(8)));
typedef unsigned short u16x4 __attribute__((ext_vector_type(4)));
typedef unsigned short u16x8 __attribute__((ext_vector_type(8)));

// fp16 bit helpers
__device__ __forceinline__ unsigned short f32_to_f16u(float v) {
  union { _Float16 h; unsigned short u; } cv; cv.h = (_Float16)v; return cv.u;
}
__device__ __forceinline__ float f16u_to_f32(unsigned short u) {
  union { _Float16 h; unsigned short u; } cv; cv.u = u; return (float)cv.h;
}

// async global->LDS, 16B per lane; LDS dest = wave-uniform base + lane*16
__device__ __forceinline__ void glds16(const void* g, void* l) {
  __builtin_amdgcn_global_load_lds((const __attribute__((address_space(1))) void*)g,
                                   (__attribute__((address_space(3))) void*)l, 16, 0, 0);
}

// ---------------------------------------------------------------------------
// Kernel 0: x (fp32 [B,C,N]) -> fp16 xf [B,C,N] and transposed xfT [B,N,C].
// 64x64 tiles, float4 loads, LDS transpose.  (unchanged — already ~mem-bound)
// ---------------------------------------------------------------------------
__global__ __launch_bounds__(256) void convert_kernel(const float* __restrict__ x,
                                                      unsigned short* __restrict__ xf,
                                                      unsigned short* __restrict__ xfT) {
  const int b = blockIdx.z;
  const int cy = blockIdx.y * 64;   // C tile origin
  const int nx = blockIdx.x * 64;   // N tile origin
  const int t = threadIdx.x;
  const int r = t >> 4, c4 = (t & 15) * 4;

  __shared__ unsigned T[64][65];    // u32 slots: 2-way-max banking both phases

#pragma unroll
  for (int rr = 0; rr < 64; rr += 16) {
    const int row = rr + r;
    const size_t gi = ((size_t)b * C + cy + row) * N + nx + c4;
    const float4 v = *(const float4*)&x[gi];
    u16x4 h;
    h[0] = f32_to_f16u(v.x); h[1] = f32_to_f16u(v.y);
    h[2] = f32_to_f16u(v.z); h[3] = f32_to_f16u(v.w);
    *(u16x4*)&xf[gi] = h;
    T[row][c4 + 0] = h[0]; T[row][c4 + 1] = h[1];
    T[row][c4 + 2] = h[2]; T[row][c4 + 3] = h[3];
  }
  __syncthreads();
#pragma unroll
  for (int rr = 0; rr < 64; rr += 16) {
    const int nrow = rr + r;
    u16x4 o;
    o[0] = (unsigned short)T[c4 + 0][nrow]; o[1] = (unsigned short)T[c4 + 1][nrow];
    o[2] = (unsigned short)T[c4 + 2][nrow]; o[3] = (unsigned short)T[c4 + 3][nrow];
    *(u16x4*)&xfT[((size_t)b * N + nx + nrow) * C + cy + c4] = o;
  }
}

// ---------------------------------------------------------------------------
// Kernel 1 (FULLY FUSED, pipelined): G = F*F^T -> softmax -> A (LDS) -> E=A*F
// -> out = beta*E + x.
// Phase 1: 4-buffer glds ring (Atile space aliased as buffers 2,3 — dead in
//          phase 1), prefetch depth 3, counted s_waitcnt vmcnt(4)+raw barrier
//          (never drains to 0 mid-loop).
// Phase 2: Atile live -> 2 LDS buffers + T14 reg-staging (global->VGPR issued
//          one iter early, ds_write just before the barrier; compiler inserts
//          the counted vmcnt for the reg dep).  LDS total 128 KB, 1 block/CU,
//          16 waves (4/SIMD).
// ---------------------------------------------------------------------------
__global__ __launch_bounds__(1024, 4) void gram_soft_av(const unsigned short* __restrict__ xf,
                                                        const unsigned short* __restrict__ xfT,
                                                        const float* __restrict__ beta,
                                                        float* __restrict__ out) {
  const int l = blockIdx.x;
  const int xcd = l & 7, seq = l >> 3;     // 32 blocks per XCD
  const int b = xcd + 8 * (seq >> 3);      // 4 batch-groups per XCD (L2 reuse)
  const int i0 = (seq & 7) * 64;           // row-tile origin

  const unsigned short* __restrict__ Fh = xf  + (size_t)b * C * N;
  const unsigned short* __restrict__ FT = xfT + (size_t)b * N * C;
  float* __restrict__ ob = out + (size_t)b * C * N;

  // 4 x 32 KB staging buffers; Pb[2..3] double as the 64 KB fp16 Atile.
  __shared__ __align__(16) unsigned short Pb[4][512 * 32];   // 128 KB
  unsigned short* Atile = &Pb[2][0];                         // 64 x 512 fp16

  const int t = threadIdx.x, wave = t >> 6, lane = t & 63;
  const int wi = wave >> 3;                // 0..1: 32-row half
  const int wj = wave & 7;                 // 0..7: 64-col strip
  const int lrow = lane & 15, quad = lane >> 4;
  const int srow = lane >> 2;                              // row in 16-row chunk
  const int sel  = ((lane & 3) ^ ((lane >> 3) & 3)) * 8;   // swizzled src granule

  f32x4 acc[2][4] = {};   // [ti: 16-row tiles][tj: 16-col tiles]

  // ========================= Phase 1: Gram G = F F^T =========================
#define STAGE1(k0, nb)                                                    \
  {                                                                       \
    _Pragma("unroll")                                                     \
    for (int cc = 0; cc < 2; ++cc) {                                      \
      const int chunk = wave * 2 + cc;                                    \
      const int row = chunk * 16 + srow;                                  \
      glds16(Fh + (size_t)row * N + (k0) + sel, &Pb[nb][chunk * 512]);    \
    }                                                                     \
  }

  STAGE1(0, 0);
  STAGE1(32, 1);
  STAGE1(64, 2);

  for (int it = 0; it < 32; ++it) {
    const int k0 = it * 32;
    // stage(it) landed; stage(it+1),(it+2) (2 glds each) stay in flight
    if (it < 30)       asm volatile("s_waitcnt vmcnt(4)" ::: "memory");
    else if (it == 30) asm volatile("s_waitcnt vmcnt(2)" ::: "memory");
    else               asm volatile("s_waitcnt vmcnt(0)" ::: "memory");
    __builtin_amdgcn_s_barrier();   // all waves staged it; readers of (it+3)&3 done
    if (it + 3 < 32) STAGE1(k0 + 96, (it + 3) & 3);

    const unsigned short* __restrict__ Pc = Pb[it & 3];
    f16x8 ah[2], bh[4];
#pragma unroll
    for (int ti = 0; ti < 2; ++ti) {
      const int r = i0 + wi * 32 + ti * 16 + lrow;
      ah[ti] = *(const f16x8*)&Pc[r * 32 + (quad ^ ((r >> 1) & 3)) * 8];
    }
#pragma unroll
    for (int tj = 0; tj < 4; ++tj) {
      const int r = wj * 64 + tj * 16 + lrow;
      bh[tj] = *(const f16x8*)&Pc[r * 32 + (quad ^ ((r >> 1) & 3)) * 8];
    }
#pragma unroll
    for (int ti = 0; ti < 2; ++ti)
#pragma unroll
      for (int tj = 0; tj < 4; ++tj)
        acc[ti][tj] = __builtin_amdgcn_mfma_f32_16x16x32_f16(ah[ti], bh[tj], acc[ti][tj], 0, 0, 0);
  }
#undef STAGE1

  // ==================== fused softmax (rows complete in block) ===============
  __syncthreads();                    // all MFMA LDS reads done; reuse LDS
  float* red = (float*)&Pb[0][0];     // 16 waves x 32 row-slots
  float* fin = red + 512;             // 64 finals

  // per-lane min over its cols; rows rs = wi*32 + ti*16 + quad*4 + rr
  float m[8];
#pragma unroll
  for (int ti = 0; ti < 2; ++ti)
#pragma unroll
    for (int rr = 0; rr < 4; ++rr)
      m[ti * 4 + rr] = fminf(fminf(acc[ti][0][rr], acc[ti][1][rr]),
                             fminf(acc[ti][2][rr], acc[ti][3][rr]));
#pragma unroll
  for (int o = 1; o < 16; o <<= 1)
#pragma unroll
    for (int s = 0; s < 8; ++s) m[s] = fminf(m[s], __shfl_xor(m[s], o, 64));
  if (lrow == 0)
#pragma unroll
    for (int ti = 0; ti < 2; ++ti)
#pragma unroll
      for (int rr = 0; rr < 4; ++rr)
        red[wave * 32 + ti * 16 + quad * 4 + rr] = m[ti * 4 + rr];
  __syncthreads();
  if (t < 64) {
    const int wig = t >> 5, loc = t & 31;
    float v = red[(wig * 8) * 32 + loc];
#pragma unroll
    for (int j = 1; j < 8; ++j) v = fminf(v, red[(wig * 8 + j) * 32 + loc]);
    fin[t] = v;
  }
  __syncthreads();

  // exponentiate in place, per-lane partial row sums
  float sm[8];
#pragma unroll
  for (int ti = 0; ti < 2; ++ti)
#pragma unroll
    for (int rr = 0; rr < 4; ++rr) {
      const float mn = fin[wi * 32 + ti * 16 + quad * 4 + rr];
      float s = 0.f;
#pragma unroll
      for (int tj = 0; tj < 4; ++tj) {
        const float e = __expf(mn - acc[ti][tj][rr]);
        acc[ti][tj][rr] = e;
        s += e;
      }
      sm[ti * 4 + rr] = s;
    }
#pragma unroll
  for (int o = 1; o < 16; o <<= 1)
#pragma unroll
    for (int s = 0; s < 8; ++s) sm[s] += __shfl_xor(sm[s], o, 64);
  if (lrow == 0)
#pragma unroll
    for (int ti = 0; ti < 2; ++ti)
#pragma unroll
      for (int rr = 0; rr < 4; ++rr)
        red[wave * 32 + ti * 16 + quad * 4 + rr] = sm[ti * 4 + rr];
  __syncthreads();
  if (t < 64) {
    const int wig = t >> 5, loc = t & 31;
    float v = 0.f;
#pragma unroll
    for (int j = 0; j < 8; ++j) v += red[(wig * 8 + j) * 32 + loc];
    fin[t] = 1.0f / v;
  }
  __syncthreads();

  // scale + write fp16 A into LDS Atile (= Pb[2..3]), XOR-swizzled:
  // element (r,c) at r*512 + ((c>>3 ^ (r&7))*8 | (c&7)).
#pragma unroll
  for (int ti = 0; ti < 2; ++ti)
#pragma unroll
    for (int rr = 0; rr < 4; ++rr) {
      const float inv = fin[wi * 32 + ti * 16 + quad * 4 + rr];
      const int rl = wi * 32 + ti * 16 + quad * 4 + rr;   // local row 0..63
#pragma unroll
      for (int tj = 0; tj < 4; ++tj) {
        const int gcol = wj * 64 + tj * 16 + lrow;
        Atile[rl * 512 + ((((gcol >> 3) ^ (rl & 7)) << 3) | (gcol & 7))] =
            f32_to_f16u(acc[ti][tj][rr] * inv);
      }
    }
  __syncthreads();                    // Atile visible to all waves; red/fin dead

  // ======================= Phase 2: E = A*F, out = beta*E + x ================
  // 2 column-half passes of 512; reg-staged depth-2 pipeline into Pb[0..1].
  const float bv = beta[0];

  for (int jp = 0; jp < 2; ++jp) {
    f32x4 eacc[2][4] = {};
    u16x8 rsA[2];
#define LOADR_E(k0)                                                            \
    {                                                                          \
      _Pragma("unroll")                                                        \
      for (int cc = 0; cc < 2; ++cc) {                                         \
        const int chunk = wave * 2 + cc;                                       \
        const int row = chunk * 16 + srow;                                     \
        rsA[cc] = *(const u16x8*)&FT[(size_t)(jp * 512 + row) * C + (k0) + sel]; \
      }                                                                        \
    }
#define WRITER_E(nb)                                                           \
    {                                                                          \
      _Pragma("unroll")                                                        \
      for (int cc = 0; cc < 2; ++cc) {                                         \
        const int chunk = wave * 2 + cc;                                       \
        *(u16x8*)&Pb[nb][chunk * 512 + lane * 8] = rsA[cc];                    \
      }                                                                        \
    }
    LOADR_E(0);
    WRITER_E(0);          // compiler inserts vmcnt wait for rsA dep
    LOADR_E(32);          // prefetch next panel into regs
    asm volatile("s_waitcnt lgkmcnt(0)" ::: "memory");
    __builtin_amdgcn_s_barrier();

    for (int it = 0; it < 16; ++it) {
      const int k0 = it * 32;
      const unsigned short* __restrict__ Pc = Pb[it & 1];
      f16x8 ah[2], bh[4];
#pragma unroll
      for (int ti = 0; ti < 2; ++ti) {
        const int ra = wi * 32 + ti * 16 + lrow;          // A row 0..63
        ah[ti] = *(const f16x8*)&Atile[ra * 512 + ((((k0 >> 3) | quad) ^ (ra & 7)) << 3)];
      }
#pragma unroll
      for (int tj = 0; tj < 4; ++tj) {
        const int rb = wj * 64 + tj * 16 + lrow;          // F^T row within half
        bh[tj] = *(const f16x8*)&Pc[rb * 32 + ((quad ^ ((rb >> 1) & 3)) << 3)];
      }
#pragma unroll
      for (int ti = 0; ti < 2; ++ti)
#pragma unroll
        for (int tj = 0; tj < 4; ++tj)
          eacc[ti][tj] = __builtin_amdgcn_mfma_f32_16x16x32_f16(ah[ti], bh[tj], eacc[ti][tj], 0, 0, 0);

      if (it + 1 < 16) WRITER_E((it + 1) & 1);   // stage next panel from regs
      if (it + 2 < 16) LOADR_E(k0 + 64);         // prefetch next-next into regs
      asm volatile("s_waitcnt lgkmcnt(0)" ::: "memory");  // drain ds_write
      __builtin_amdgcn_s_barrier();
    }
#undef LOADR_E
#undef WRITER_E

    // Epilogue: per-wave LDS transpose of each 16x64 strip -> float4 I/O,
    // residual from fp16 xf (|err| <= |x|*4.9e-4), nontemporal stores.
    float* fs = (float*)&Pb[0][0] + wave * 1024;   // 4 KB per wave
#pragma unroll
    for (int ti = 0; ti < 2; ++ti) {
#pragma unroll
      for (int tj = 0; tj < 4; ++tj)
#pragma unroll
        for (int r = 0; r < 4; ++r)
          fs[(quad * 4 + r) * 64 + tj * 16 + lrow] = eacc[ti][tj][r];
      __syncthreads();
#pragma unroll
      for (int p = 0; p < 4; ++p) {
        const int f = p * 64 + lane;
        const int rr2 = f >> 4, cc4 = (f & 15) * 4;
        const f32x4 e = *(const f32x4*)&fs[rr2 * 64 + cc4];
        const int gr = i0 + wi * 32 + ti * 16 + rr2;
        const int gc = jp * 512 + wj * 64 + cc4;
        const size_t o = (size_t)gr * N + gc;
        const u16x4 xv = *(const u16x4*)&Fh[o];
        f32x4 ov;
        ov[0] = fmaf(bv, e[0], f16u_to_f32(xv[0]));
        ov[1] = fmaf(bv, e[1], f16u_to_f32(xv[1]));
        ov[2] = fmaf(bv, e[2], f16u_to_f32(xv[2]));
        ov[3] = fmaf(bv, e[3], f16u_to_f32(xv[3]));
        __builtin_nontemporal_store(ov, (f32x4*)&ob[o]);
      }
      __syncthreads();
    }
  }
}

// ---------------------------------------------------------------------------
extern "C" void kernel_launch(void* const* d_in, const int* in_sizes, int n_in,
                              void* d_out, int out_size, void* d_ws, size_t ws_size,
                              hipStream_t stream) {
  const float* x    = (const float*)d_in[0];
  const float* beta = (const float*)d_in[1];
  float* out = (float*)d_out;

  char* ws = (char*)d_ws;
  unsigned short* xf  = (unsigned short*)ws; ws += (size_t)B * C * N * 2;  // 32 MB
  unsigned short* xfT = (unsigned short*)ws;                               // 32 MB

  convert_kernel<<<dim3(N / 64, C / 64, B), dim3(256),  0, stream>>>(x, xf, xfT);
  gram_soft_av  <<<dim3(256),               dim3(1024), 0, stream>>>(xf, xfT, beta, out);
}

// Round 3
// 174.908 us; speedup vs baseline: 1.0375x; 1.0142x over previous
//
#include <hip/hip_runtime.h>
#include <math.h>

// Problem constants (fixed by reference setup_inputs)
constexpr int B = 32, C = 512, N = 1024;   // N = H*W

typedef float f32x4 __attribute__((ext_vector_type(4)));
typedef _Float16 f16x8 __attribute__((ext_vector_type(8)));
typedef unsigned short u16x4 __attribute__((ext_vector_type(4)));
typedef unsigned short u16x8 __attribute__((ext_vector_type(8)));

// fp16 bit helpers
__device__ __forceinline__ unsigned short f32_to_f16u(float v) {
  union { _Float16 h; unsigned short u; } cv; cv.h = (_Float16)v; return cv.u;
}
__device__ __forceinline__ float f16u_to_f32(unsigned short u) {
  union { _Float16 h; unsigned short u; } cv; cv.u = u; return (float)cv.h;
}

// async global->LDS, 16B per lane; LDS dest = wave-uniform base + lane*16
__device__ __forceinline__ void glds16(const void* g, void* l) {
  __builtin_amdgcn_global_load_lds((const __attribute__((address_space(1))) void*)g,
                                   (__attribute__((address_space(3))) void*)l, 16, 0, 0);
}

// ---------------------------------------------------------------------------
// Kernel 0: x (fp32 [B,C,N]) -> fp16 xf [B,C,N] and transposed xfT [B,N,C].
// 64x64 tiles, float4 loads, LDS transpose.  (unchanged — already ~mem-bound)
// ---------------------------------------------------------------------------
__global__ __launch_bounds__(256) void convert_kernel(const float* __restrict__ x,
                                                      unsigned short* __restrict__ xf,
                                                      unsigned short* __restrict__ xfT) {
  const int b = blockIdx.z;
  const int cy = blockIdx.y * 64;   // C tile origin
  const int nx = blockIdx.x * 64;   // N tile origin
  const int t = threadIdx.x;
  const int r = t >> 4, c4 = (t & 15) * 4;

  __shared__ unsigned T[64][65];    // u32 slots: 2-way-max banking both phases

#pragma unroll
  for (int rr = 0; rr < 64; rr += 16) {
    const int row = rr + r;
    const size_t gi = ((size_t)b * C + cy + row) * N + nx + c4;
    const float4 v = *(const float4*)&x[gi];
    u16x4 h;
    h[0] = f32_to_f16u(v.x); h[1] = f32_to_f16u(v.y);
    h[2] = f32_to_f16u(v.z); h[3] = f32_to_f16u(v.w);
    *(u16x4*)&xf[gi] = h;
    T[row][c4 + 0] = h[0]; T[row][c4 + 1] = h[1];
    T[row][c4 + 2] = h[2]; T[row][c4 + 3] = h[3];
  }
  __syncthreads();
#pragma unroll
  for (int rr = 0; rr < 64; rr += 16) {
    const int nrow = rr + r;
    u16x4 o;
    o[0] = (unsigned short)T[c4 + 0][nrow]; o[1] = (unsigned short)T[c4 + 1][nrow];
    o[2] = (unsigned short)T[c4 + 2][nrow]; o[3] = (unsigned short)T[c4 + 3][nrow];
    *(u16x4*)&xfT[((size_t)b * N + nx + nrow) * C + cy + c4] = o;
  }
}

// ---------------------------------------------------------------------------
// Kernel 1 (FULLY FUSED, 8-wave 64x64 tiles): G = F*F^T -> softmax -> A (LDS)
// -> E=A*F -> out = beta*E + x.
// LDS-read economy: 8 waves (1 wi x 8 wj), wave tile 64x64 = 4x4 MFMA frags:
// per K32 per CU 64 ds_read_b128 (768 cyc) vs 128 MFMA (620 cyc) — near
// balance, vs 96 reads (1152 cyc) for the old 16-wave 32x64 layout.
// Phase 1: 4-buffer glds ring depth-3, counted vmcnt(8) (never 0 mid-loop).
// Phase 2: Atile live -> 2 buffers + reg-staging depth-2.
// LDS 128 KB, 512 threads, 2 waves/SIMD.
// ---------------------------------------------------------------------------
__global__ __launch_bounds__(512, 2) void gram_soft_av(const unsigned short* __restrict__ xf,
                                                       const unsigned short* __restrict__ xfT,
                                                       const float* __restrict__ beta,
                                                       float* __restrict__ out) {
  const int l = blockIdx.x;
  const int xcd = l & 7, seq = l >> 3;     // 32 blocks per XCD
  const int b = xcd + 8 * (seq >> 3);      // 4 batch-groups per XCD (L2 reuse)
  const int i0 = (seq & 7) * 64;           // row-tile origin

  const unsigned short* __restrict__ Fh = xf  + (size_t)b * C * N;
  const unsigned short* __restrict__ FT = xfT + (size_t)b * N * C;
  float* __restrict__ ob = out + (size_t)b * C * N;

  // 4 x 32 KB staging buffers; Pb[2..3] double as the 64 KB fp16 Atile.
  __shared__ __align__(16) unsigned short Pb[4][512 * 32];   // 128 KB
  unsigned short* Atile = &Pb[2][0];                         // 64 x 512 fp16

  const int t = threadIdx.x, wave = t >> 6, lane = t & 63;   // 8 waves
  const int lrow = lane & 15, quad = lane >> 4;
  const int srow = lane >> 2;                              // row in 16-row chunk
  const int sel  = ((lane & 3) ^ ((lane >> 3) & 3)) * 8;   // swizzled src granule

  f32x4 acc[4][4] = {};   // wave tile 64x64: [ti 4 row-frags][tj 4 col-frags]

  // ========================= Phase 1: Gram G = F F^T =========================
#define STAGE1(k0, nb)                                                    \
  {                                                                       \
    _Pragma("unroll")                                                     \
    for (int cc = 0; cc < 4; ++cc) {                                      \
      const int chunk = wave * 4 + cc;                                    \
      const int row = chunk * 16 + srow;                                  \
      glds16(Fh + (size_t)row * N + (k0) + sel, &Pb[nb][chunk * 512]);    \
    }                                                                     \
  }

  STAGE1(0, 0);
  STAGE1(32, 1);
  STAGE1(64, 2);

  for (int it = 0; it < 32; ++it) {
    const int k0 = it * 32;
    // stage(it) landed; stage(it+1),(it+2) (4 glds each) stay in flight
    if (it < 30)       asm volatile("s_waitcnt vmcnt(8)" ::: "memory");
    else if (it == 30) asm volatile("s_waitcnt vmcnt(4)" ::: "memory");
    else               asm volatile("s_waitcnt vmcnt(0)" ::: "memory");
    __builtin_amdgcn_s_barrier();   // all waves staged it; readers of (it+3)&3 done
    if (it + 3 < 32) STAGE1(k0 + 96, (it + 3) & 3);

    const unsigned short* __restrict__ Pc = Pb[it & 3];
    f16x8 ah[4], bh[4];
#pragma unroll
    for (int ti = 0; ti < 4; ++ti) {
      const int r = i0 + ti * 16 + lrow;
      ah[ti] = *(const f16x8*)&Pc[r * 32 + (quad ^ ((r >> 1) & 3)) * 8];
    }
#pragma unroll
    for (int tj = 0; tj < 4; ++tj) {
      const int r = wave * 64 + tj * 16 + lrow;
      bh[tj] = *(const f16x8*)&Pc[r * 32 + (quad ^ ((r >> 1) & 3)) * 8];
    }
    __builtin_amdgcn_s_setprio(1);
#pragma unroll
    for (int ti = 0; ti < 4; ++ti)
#pragma unroll
      for (int tj = 0; tj < 4; ++tj)
        acc[ti][tj] = __builtin_amdgcn_mfma_f32_16x16x32_f16(ah[ti], bh[tj], acc[ti][tj], 0, 0, 0);
    __builtin_amdgcn_s_setprio(0);
  }
#undef STAGE1

  // ==================== fused softmax (rows complete in block) ===============
  // Each wave holds all 64 rows x its 64-col strip; row = ti*16 + quad*4 + rr.
  __syncthreads();                    // all MFMA LDS reads done; reuse LDS
  float* red = (float*)&Pb[0][0];     // 8 waves x 64 row-slots
  float* fin = red + 512;             // 64 finals

  float m[16];
#pragma unroll
  for (int ti = 0; ti < 4; ++ti)
#pragma unroll
    for (int rr = 0; rr < 4; ++rr)
      m[ti * 4 + rr] = fminf(fminf(acc[ti][0][rr], acc[ti][1][rr]),
                             fminf(acc[ti][2][rr], acc[ti][3][rr]));
#pragma unroll
  for (int o = 1; o < 16; o <<= 1)
#pragma unroll
    for (int s = 0; s < 16; ++s) m[s] = fminf(m[s], __shfl_xor(m[s], o, 64));
  if (lrow == 0)
#pragma unroll
    for (int ti = 0; ti < 4; ++ti)
#pragma unroll
      for (int rr = 0; rr < 4; ++rr)
        red[wave * 64 + ti * 16 + quad * 4 + rr] = m[ti * 4 + rr];
  __syncthreads();
  if (t < 64) {
    float v = red[t];
#pragma unroll
    for (int j = 1; j < 8; ++j) v = fminf(v, red[j * 64 + t]);
    fin[t] = v;
  }
  __syncthreads();

  // exponentiate in place, per-lane partial row sums
  float sm[16];
#pragma unroll
  for (int ti = 0; ti < 4; ++ti)
#pragma unroll
    for (int rr = 0; rr < 4; ++rr) {
      const float mn = fin[ti * 16 + quad * 4 + rr];
      float s = 0.f;
#pragma unroll
      for (int tj = 0; tj < 4; ++tj) {
        const float e = __expf(mn - acc[ti][tj][rr]);
        acc[ti][tj][rr] = e;
        s += e;
      }
      sm[ti * 4 + rr] = s;
    }
#pragma unroll
  for (int o = 1; o < 16; o <<= 1)
#pragma unroll
    for (int s = 0; s < 16; ++s) sm[s] += __shfl_xor(sm[s], o, 64);
  if (lrow == 0)
#pragma unroll
    for (int ti = 0; ti < 4; ++ti)
#pragma unroll
      for (int rr = 0; rr < 4; ++rr)
        red[wave * 64 + ti * 16 + quad * 4 + rr] = sm[ti * 4 + rr];
  __syncthreads();
  if (t < 64) {
    float v = 0.f;
#pragma unroll
    for (int j = 0; j < 8; ++j) v += red[j * 64 + t];
    fin[t] = 1.0f / v;
  }
  __syncthreads();

  // scale + write fp16 A into LDS Atile (= Pb[2..3]), XOR-swizzled:
  // element (r,c) at r*512 + ((c>>3 ^ (r&7))*8 | (c&7)).
#pragma unroll
  for (int ti = 0; ti < 4; ++ti)
#pragma unroll
    for (int rr = 0; rr < 4; ++rr) {
      const float inv = fin[ti * 16 + quad * 4 + rr];
      const int rl = ti * 16 + quad * 4 + rr;             // local row 0..63
#pragma unroll
      for (int tj = 0; tj < 4; ++tj) {
        const int gcol = wave * 64 + tj * 16 + lrow;
        Atile[rl * 512 + ((((gcol >> 3) ^ (rl & 7)) << 3) | (gcol & 7))] =
            f32_to_f16u(acc[ti][tj][rr] * inv);
      }
    }
  __syncthreads();                    // Atile visible to all waves; red/fin dead

  // ======================= Phase 2: E = A*F, out = beta*E + x ================
  // 2 column-half passes of 512; reg-staged depth-2 pipeline into Pb[0..1].
  const float bv = beta[0];

  for (int jp = 0; jp < 2; ++jp) {
    f32x4 eacc[4][4] = {};
    u16x8 rsA[4];
#define LOADR_E(k0)                                                            \
    {                                                                          \
      _Pragma("unroll")                                                        \
      for (int cc = 0; cc < 4; ++cc) {                                         \
        const int chunk = wave * 4 + cc;                                       \
        const int row = chunk * 16 + srow;                                     \
        rsA[cc] = *(const u16x8*)&FT[(size_t)(jp * 512 + row) * C + (k0) + sel]; \
      }                                                                        \
    }
#define WRITER_E(nb)                                                           \
    {                                                                          \
      _Pragma("unroll")                                                        \
      for (int cc = 0; cc < 4; ++cc) {                                         \
        const int chunk = wave * 4 + cc;                                       \
        *(u16x8*)&Pb[nb][chunk * 512 + lane * 8] = rsA[cc];                    \
      }                                                                        \
    }
    LOADR_E(0);
    WRITER_E(0);          // compiler inserts vmcnt wait for rsA dep
    LOADR_E(32);          // prefetch next panel into regs
    asm volatile("s_waitcnt lgkmcnt(0)" ::: "memory");
    __builtin_amdgcn_s_barrier();

    for (int it = 0; it < 16; ++it) {
      const int k0 = it * 32;
      const unsigned short* __restrict__ Pc = Pb[it & 1];
      f16x8 ah[4], bh[4];
#pragma unroll
      for (int ti = 0; ti < 4; ++ti) {
        const int ra = ti * 16 + lrow;                    // A row 0..63
        ah[ti] = *(const f16x8*)&Atile[ra * 512 + ((((k0 >> 3) + quad) ^ (ra & 7)) << 3)];
      }
#pragma unroll
      for (int tj = 0; tj < 4; ++tj) {
        const int rb = wave * 64 + tj * 16 + lrow;        // F^T row within half
        bh[tj] = *(const f16x8*)&Pc[rb * 32 + ((quad ^ ((rb >> 1) & 3)) << 3)];
      }
      __builtin_amdgcn_s_setprio(1);
#pragma unroll
      for (int ti = 0; ti < 4; ++ti)
#pragma unroll
        for (int tj = 0; tj < 4; ++tj)
          eacc[ti][tj] = __builtin_amdgcn_mfma_f32_16x16x32_f16(ah[ti], bh[tj], eacc[ti][tj], 0, 0, 0);
      __builtin_amdgcn_s_setprio(0);

      if (it + 1 < 16) WRITER_E((it + 1) & 1);   // stage next panel from regs
      if (it + 2 < 16) LOADR_E(k0 + 64);         // prefetch next-next into regs
      asm volatile("s_waitcnt lgkmcnt(0)" ::: "memory");  // drain ds ops
      __builtin_amdgcn_s_barrier();
    }
#undef LOADR_E
#undef WRITER_E

    // Epilogue: per-wave LDS transpose (own 4 KB region -> no block barriers),
    // residual from fp16 xf (|err| <= |x|*4.9e-4), nontemporal stores.
    float* fs = (float*)&Pb[0][0] + wave * 1024;   // 4 KB per wave
#pragma unroll
    for (int ti = 0; ti < 4; ++ti) {
#pragma unroll
      for (int tj = 0; tj < 4; ++tj)
#pragma unroll
        for (int r = 0; r < 4; ++r)
          fs[(quad * 4 + r) * 64 + tj * 16 + lrow] = eacc[ti][tj][r];
      asm volatile("s_waitcnt lgkmcnt(0)" ::: "memory");   // per-wave RAW fence
#pragma unroll
      for (int p = 0; p < 4; ++p) {
        const int f = p * 64 + lane;
        const int rr2 = f >> 4, cc4 = (f & 15) * 4;
        const f32x4 e = *(const f32x4*)&fs[rr2 * 64 + cc4];
        const int gr = i0 + ti * 16 + rr2;
        const int gc = jp * 512 + wave * 64 + cc4;
        const size_t o = (size_t)gr * N + gc;
        const u16x4 xv = *(const u16x4*)&Fh[o];
        f32x4 ov;
        ov[0] = fmaf(bv, e[0], f16u_to_f32(xv[0]));
        ov[1] = fmaf(bv, e[1], f16u_to_f32(xv[1]));
        ov[2] = fmaf(bv, e[2], f16u_to_f32(xv[2]));
        ov[3] = fmaf(bv, e[3], f16u_to_f32(xv[3]));
        __builtin_nontemporal_store(ov, (f32x4*)&ob[o]);
      }
    }
  }
}

// ---------------------------------------------------------------------------
extern "C" void kernel_launch(void* const* d_in, const int* in_sizes, int n_in,
                              void* d_out, int out_size, void* d_ws, size_t ws_size,
                              hipStream_t stream) {
  const float* x    = (const float*)d_in[0];
  const float* beta = (const float*)d_in[1];
  float* out = (float*)d_out;

  char* ws = (char*)d_ws;
  unsigned short* xf  = (unsigned short*)ws; ws += (size_t)B * C * N * 2;  // 32 MB
  unsigned short* xfT = (unsigned short*)ws;                               // 32 MB

  convert_kernel<<<dim3(N / 64, C / 64, B), dim3(256), 0, stream>>>(x, xf, xfT);
  gram_soft_av  <<<dim3(256),               dim3(512), 0, stream>>>(xf, xfT, beta, out);
}

// Round 5
// 170.957 us; speedup vs baseline: 1.0614x; 1.0231x over previous
//
#include <hip/hip_runtime.h>
#include <math.h>

// Problem constants (fixed by reference setup_inputs)
constexpr int B = 32, C = 512, N = 1024;   // N = H*W

typedef float f32x4 __attribute__((ext_vector_type(4)));
typedef _Float16 f16x8 __attribute__((ext_vector_type(8)));
typedef unsigned short u16x4 __attribute__((ext_vector_type(4)));
typedef unsigned short u16x8 __attribute__((ext_vector_type(8)));

// fp16 bit helpers
__device__ __forceinline__ unsigned short f32_to_f16u(float v) {
  union { _Float16 h; unsigned short u; } cv; cv.h = (_Float16)v; return cv.u;
}
__device__ __forceinline__ float f16u_to_f32(unsigned short u) {
  union { _Float16 h; unsigned short u; } cv; cv.u = u; return (float)cv.h;
}

// async global->LDS, 16B per lane; LDS dest = wave-uniform base + lane*16
__device__ __forceinline__ void glds16(const void* g, void* l) {
  __builtin_amdgcn_global_load_lds((const __attribute__((address_space(1))) void*)g,
                                   (__attribute__((address_space(3))) void*)l, 16, 0, 0);
}

// ---------------------------------------------------------------------------
// Kernel 0: x (fp32 [B,C,N]) -> fp16 xf [B,C,N] and transposed xfT [B,N,C].
// 64x64 tiles, float4 loads, LDS transpose.  (unchanged — already ~mem-bound)
// ---------------------------------------------------------------------------
__global__ __launch_bounds__(256) void convert_kernel(const float* __restrict__ x,
                                                      unsigned short* __restrict__ xf,
                                                      unsigned short* __restrict__ xfT) {
  const int b = blockIdx.z;
  const int cy = blockIdx.y * 64;   // C tile origin
  const int nx = blockIdx.x * 64;   // N tile origin
  const int t = threadIdx.x;
  const int r = t >> 4, c4 = (t & 15) * 4;

  __shared__ unsigned T[64][65];    // u32 slots: 2-way-max banking both phases

#pragma unroll
  for (int rr = 0; rr < 64; rr += 16) {
    const int row = rr + r;
    const size_t gi = ((size_t)b * C + cy + row) * N + nx + c4;
    const float4 v = *(const float4*)&x[gi];
    u16x4 h;
    h[0] = f32_to_f16u(v.x); h[1] = f32_to_f16u(v.y);
    h[2] = f32_to_f16u(v.z); h[3] = f32_to_f16u(v.w);
    *(u16x4*)&xf[gi] = h;
    T[row][c4 + 0] = h[0]; T[row][c4 + 1] = h[1];
    T[row][c4 + 2] = h[2]; T[row][c4 + 3] = h[3];
  }
  __syncthreads();
#pragma unroll
  for (int rr = 0; rr < 64; rr += 16) {
    const int nrow = rr + r;
    u16x4 o;
    o[0] = (unsigned short)T[c4 + 0][nrow]; o[1] = (unsigned short)T[c4 + 1][nrow];
    o[2] = (unsigned short)T[c4 + 2][nrow]; o[3] = (unsigned short)T[c4 + 3][nrow];
    *(u16x4*)&xfT[((size_t)b * N + nx + nrow) * C + cy + c4] = o;
  }
}

// ---------------------------------------------------------------------------
// Kernel 1 (FULLY FUSED, reg-double-buffered): G = F*F^T -> softmax -> A (LDS)
// -> E=A*F -> out = beta*E + x.
// Three pipeline levels: glds 4-buffer ring (depth 3) / LDS / register frag
// double-buffer.  Body j: MFMA regs(j) [NO lgkm dependency] || ds_read
// frags(j+1) || glds stage(j+4).  vmcnt counted so stage(j+1) has landed at
// body j's barrier.  8 waves x 64x64 tile, LDS 128 KB, 512 thr, 2 waves/SIMD.
// (Re-run of R3 candidate: R4 bench was a container-acquisition failure, not
//  a kernel verdict — logic re-audited: vmcnt ledger exact, barriers uniform,
//  buffer lifetimes fenced, DS in-order per wave.)
// ---------------------------------------------------------------------------
__global__ __launch_bounds__(512, 2) void gram_soft_av(const unsigned short* __restrict__ xf,
                                                       const unsigned short* __restrict__ xfT,
                                                       const float* __restrict__ beta,
                                                       float* __restrict__ out) {
  const int l = blockIdx.x;
  const int xcd = l & 7, seq = l >> 3;     // 32 blocks per XCD
  const int b = xcd + 8 * (seq >> 3);      // 4 batch-groups per XCD (L2 reuse)
  const int i0 = (seq & 7) * 64;           // row-tile origin

  const unsigned short* __restrict__ Fh = xf  + (size_t)b * C * N;
  const unsigned short* __restrict__ FT = xfT + (size_t)b * N * C;
  float* __restrict__ ob = out + (size_t)b * C * N;

  // 4 x 32 KB staging buffers; Pb[2..3] double as the 64 KB fp16 Atile.
  __shared__ __align__(16) unsigned short Pb[4][512 * 32];   // 128 KB
  unsigned short* Atile = &Pb[2][0];                         // 64 x 512 fp16

  const int t = threadIdx.x, wave = t >> 6, lane = t & 63;   // 8 waves
  const int lrow = lane & 15, quad = lane >> 4;
  const int srow = lane >> 2;                              // row in 16-row chunk
  const int sel  = ((lane & 3) ^ ((lane >> 3) & 3)) * 8;   // swizzled src granule

  f32x4 acc[4][4] = {};   // wave tile 64x64: [ti 4 row-frags][tj 4 col-frags]

  // ========================= Phase 1: Gram G = F F^T =========================
#define STAGE1(k0, nb)                                                    \
  {                                                                       \
    _Pragma("unroll")                                                     \
    for (int cc = 0; cc < 4; ++cc) {                                      \
      const int chunk = wave * 4 + cc;                                    \
      const int row = chunk * 16 + srow;                                  \
      glds16(Fh + (size_t)row * N + (k0) + sel, &Pb[nb][chunk * 512]);    \
    }                                                                     \
  }

  // load MFMA fragments for K-step jj from staged buffer Pb[jj&3]
#define LOADFRAG1(AH, BH, jj)                                             \
  {                                                                       \
    const unsigned short* __restrict__ Pc = Pb[(jj) & 3];                 \
    _Pragma("unroll")                                                     \
    for (int ti = 0; ti < 4; ++ti) {                                      \
      const int r = i0 + ti * 16 + lrow;                                  \
      AH[ti] = *(const f16x8*)&Pc[r * 32 + (quad ^ ((r >> 1) & 3)) * 8];  \
    }                                                                     \
    _Pragma("unroll")                                                     \
    for (int tj = 0; tj < 4; ++tj) {                                      \
      const int r = wave * 64 + tj * 16 + lrow;                           \
      BH[tj] = *(const f16x8*)&Pc[r * 32 + (quad ^ ((r >> 1) & 3)) * 8];  \
    }                                                                     \
  }

#define MFMA16(AH, BH, ACC)                                               \
  {                                                                       \
    __builtin_amdgcn_s_setprio(1);                                        \
    _Pragma("unroll")                                                     \
    for (int ti = 0; ti < 4; ++ti)                                        \
      _Pragma("unroll")                                                   \
      for (int tj = 0; tj < 4; ++tj)                                      \
        ACC[ti][tj] = __builtin_amdgcn_mfma_f32_16x16x32_f16(AH[ti], BH[tj], ACC[ti][tj], 0, 0, 0); \
    __builtin_amdgcn_s_setprio(0);                                        \
  }

  // body j: wait (stage j+1 landed, frags j drained) -> barrier ->
  //         stage(j+4) || read frags(j+1)->NXT || MFMA(CUR = frags j)
#define P1BODY(CA, CB, NA, NB, j)                                         \
  {                                                                       \
    if ((j) < 29)       asm volatile("s_waitcnt vmcnt(8) lgkmcnt(0)" ::: "memory"); \
    else if ((j) == 29) asm volatile("s_waitcnt vmcnt(4) lgkmcnt(0)" ::: "memory"); \
    else                asm volatile("s_waitcnt vmcnt(0) lgkmcnt(0)" ::: "memory"); \
    __builtin_amdgcn_s_barrier();                                         \
    if ((j) + 4 < 32) STAGE1(((j) + 4) * 32, ((j) + 4) & 3);              \
    if ((j) + 1 < 32) LOADFRAG1(NA, NB, (j) + 1);                         \
    MFMA16(CA, CB, acc);                                                  \
  }

  STAGE1(0, 0);
  STAGE1(32, 1);
  STAGE1(64, 2);
  STAGE1(96, 3);
  asm volatile("s_waitcnt vmcnt(12)" ::: "memory");   // stage 0 landed
  __builtin_amdgcn_s_barrier();

  f16x8 a0h[4], b0h[4], a1h[4], b1h[4];
  LOADFRAG1(a0h, b0h, 0);

  for (int j = 0; j < 32; j += 2) {
    P1BODY(a0h, b0h, a1h, b1h, j);
    P1BODY(a1h, b1h, a0h, b0h, j + 1);
  }
#undef P1BODY
#undef STAGE1

  // ==================== fused softmax (rows complete in block) ===============
  // Each wave holds all 64 rows x its 64-col strip; row = ti*16 + quad*4 + rr.
  __syncthreads();                    // all MFMA LDS reads done; reuse LDS
  float* red = (float*)&Pb[0][0];     // 8 waves x 64 row-slots
  float* fin = red + 512;             // 64 finals

  float m[16];
#pragma unroll
  for (int ti = 0; ti < 4; ++ti)
#pragma unroll
    for (int rr = 0; rr < 4; ++rr)
      m[ti * 4 + rr] = fminf(fminf(acc[ti][0][rr], acc[ti][1][rr]),
                             fminf(acc[ti][2][rr], acc[ti][3][rr]));
#pragma unroll
  for (int o = 1; o < 16; o <<= 1)
#pragma unroll
    for (int s = 0; s < 16; ++s) m[s] = fminf(m[s], __shfl_xor(m[s], o, 64));
  if (lrow == 0)
#pragma unroll
    for (int ti = 0; ti < 4; ++ti)
#pragma unroll
      for (int rr = 0; rr < 4; ++rr)
        red[wave * 64 + ti * 16 + quad * 4 + rr] = m[ti * 4 + rr];
  __syncthreads();
  if (t < 64) {
    float v = red[t];
#pragma unroll
    for (int j = 1; j < 8; ++j) v = fminf(v, red[j * 64 + t]);
    fin[t] = v;
  }
  __syncthreads();

  // exponentiate in place, per-lane partial row sums
  float sm[16];
#pragma unroll
  for (int ti = 0; ti < 4; ++ti)
#pragma unroll
    for (int rr = 0; rr < 4; ++rr) {
      const float mn = fin[ti * 16 + quad * 4 + rr];
      float s = 0.f;
#pragma unroll
      for (int tj = 0; tj < 4; ++tj) {
        const float e = __expf(mn - acc[ti][tj][rr]);
        acc[ti][tj][rr] = e;
        s += e;
      }
      sm[ti * 4 + rr] = s;
    }
#pragma unroll
  for (int o = 1; o < 16; o <<= 1)
#pragma unroll
    for (int s = 0; s < 16; ++s) sm[s] += __shfl_xor(sm[s], o, 64);
  if (lrow == 0)
#pragma unroll
    for (int ti = 0; ti < 4; ++ti)
#pragma unroll
      for (int rr = 0; rr < 4; ++rr)
        red[wave * 64 + ti * 16 + quad * 4 + rr] = sm[ti * 4 + rr];
  __syncthreads();
  if (t < 64) {
    float v = 0.f;
#pragma unroll
    for (int j = 0; j < 8; ++j) v += red[j * 64 + t];
    fin[t] = 1.0f / v;
  }
  __syncthreads();

  // scale + write fp16 A into LDS Atile (= Pb[2..3]), XOR-swizzled:
  // element (r,c) at r*512 + ((c>>3 ^ (r&7))*8 | (c&7)).
#pragma unroll
  for (int ti = 0; ti < 4; ++ti)
#pragma unroll
    for (int rr = 0; rr < 4; ++rr) {
      const float inv = fin[ti * 16 + quad * 4 + rr];
      const int rl = ti * 16 + quad * 4 + rr;             // local row 0..63
#pragma unroll
      for (int tj = 0; tj < 4; ++tj) {
        const int gcol = wave * 64 + tj * 16 + lrow;
        Atile[rl * 512 + ((((gcol >> 3) ^ (rl & 7)) << 3) | (gcol & 7))] =
            f32_to_f16u(acc[ti][tj][rr] * inv);
      }
    }
  __syncthreads();                    // Atile visible to all waves; red/fin dead

  // ======================= Phase 2: E = A*F, out = beta*E + x ================
  // 2 column-half passes of 512; reg-staged depth-2 LDS pipeline into Pb[0..1]
  // + register frag double-buffer (MFMA has no lgkm dependency).
  const float bv = beta[0];

  for (int jp = 0; jp < 2; ++jp) {
    f32x4 eacc[4][4] = {};
    u16x8 rsA[4];
#define LOADR_E(k0)                                                            \
    {                                                                          \
      _Pragma("unroll")                                                        \
      for (int cc = 0; cc < 4; ++cc) {                                         \
        const int chunk = wave * 4 + cc;                                       \
        const int row = chunk * 16 + srow;                                     \
        rsA[cc] = *(const u16x8*)&FT[(size_t)(jp * 512 + row) * C + (k0) + sel]; \
      }                                                                        \
    }
#define WRITER_E(nb)                                                           \
    {                                                                          \
      _Pragma("unroll")                                                        \
      for (int cc = 0; cc < 4; ++cc) {                                         \
        const int chunk = wave * 4 + cc;                                       \
        *(u16x8*)&Pb[nb][chunk * 512 + lane * 8] = rsA[cc];                    \
      }                                                                        \
    }
#define LOADFRAG2(AH, BH, uu)                                                  \
    {                                                                          \
      const unsigned short* __restrict__ Pc = Pb[(uu) & 1];                    \
      const int kk = (uu) * 32;                                                \
      _Pragma("unroll")                                                        \
      for (int ti = 0; ti < 4; ++ti) {                                         \
        const int ra = ti * 16 + lrow;                                         \
        AH[ti] = *(const f16x8*)&Atile[ra * 512 + ((((kk >> 3) + quad) ^ (ra & 7)) << 3)]; \
      }                                                                        \
      _Pragma("unroll")                                                        \
      for (int tj = 0; tj < 4; ++tj) {                                         \
        const int rb = wave * 64 + tj * 16 + lrow;                             \
        BH[tj] = *(const f16x8*)&Pc[rb * 32 + ((quad ^ ((rb >> 1) & 3)) << 3)]; \
      }                                                                        \
    }
    // body u: write panel(u+1) from regs || load panel(u+2)->regs -> barrier
    //         -> read frags(u+1)->NXT || MFMA(CUR = frags u)
#define P2BODY(CA, CB, NA, NB, u)                                              \
    {                                                                          \
      if ((u) + 1 < 16) WRITER_E(((u) + 1) & 1);                               \
      if ((u) + 2 < 16) LOADR_E(((u) + 2) * 32);                               \
      asm volatile("s_waitcnt lgkmcnt(0)" ::: "memory");                       \
      __builtin_amdgcn_s_barrier();                                            \
      if ((u) + 1 < 16) LOADFRAG2(NA, NB, (u) + 1);                            \
      MFMA16(CA, CB, eacc);                                                    \
    }

    LOADR_E(0);
    WRITER_E(0);          // compiler inserts vmcnt wait for rsA dep
    LOADR_E(32);          // prefetch panel 1 into regs
    asm volatile("s_waitcnt lgkmcnt(0)" ::: "memory");
    __builtin_amdgcn_s_barrier();
    LOADFRAG2(a0h, b0h, 0);

    for (int u = 0; u < 16; u += 2) {
      P2BODY(a0h, b0h, a1h, b1h, u);
      P2BODY(a1h, b1h, a0h, b0h, u + 1);
    }
#undef P2BODY
#undef LOADFRAG2
#undef LOADR_E
#undef WRITER_E

    // Epilogue: per-wave LDS transpose (own 4 KB region -> no block barriers),
    // residual from fp16 xf (|err| <= |x|*4.9e-4), nontemporal stores.
    float* fs = (float*)&Pb[0][0] + wave * 1024;   // 4 KB per wave
#pragma unroll
    for (int ti = 0; ti < 4; ++ti) {
#pragma unroll
      for (int tj = 0; tj < 4; ++tj)
#pragma unroll
        for (int r = 0; r < 4; ++r)
          fs[(quad * 4 + r) * 64 + tj * 16 + lrow] = eacc[ti][tj][r];
      asm volatile("s_waitcnt lgkmcnt(0)" ::: "memory");   // per-wave RAW fence
#pragma unroll
      for (int p = 0; p < 4; ++p) {
        const int f = p * 64 + lane;
        const int rr2 = f >> 4, cc4 = (f & 15) * 4;
        const f32x4 e = *(const f32x4*)&fs[rr2 * 64 + cc4];
        const int gr = i0 + ti * 16 + rr2;
        const int gc = jp * 512 + wave * 64 + cc4;
        const size_t o = (size_t)gr * N + gc;
        const u16x4 xv = *(const u16x4*)&Fh[o];
        f32x4 ov;
        ov[0] = fmaf(bv, e[0], f16u_to_f32(xv[0]));
        ov[1] = fmaf(bv, e[1], f16u_to_f32(xv[1]));
        ov[2] = fmaf(bv, e[2], f16u_to_f32(xv[2]));
        ov[3] = fmaf(bv, e[3], f16u_to_f32(xv[3]));
        __builtin_nontemporal_store(ov, (f32x4*)&ob[o]);
      }
      asm volatile("s_waitcnt lgkmcnt(0)" ::: "memory");   // WAR vs next ds ops
    }
  }
#undef MFMA16
#undef LOADFRAG1
}

// ---------------------------------------------------------------------------
extern "C" void kernel_launch(void* const* d_in, const int* in_sizes, int n_in,
                              void* d_out, int out_size, void* d_ws, size_t ws_size,
                              hipStream_t stream) {
  const float* x    = (const float*)d_in[0];
  const float* beta = (const float*)d_in[1];
  float* out = (float*)d_out;

  char* ws = (char*)d_ws;
  unsigned short* xf  = (unsigned short*)ws; ws += (size_t)B * C * N * 2;  // 32 MB
  unsigned short* xfT = (unsigned short*)ws;                               // 32 MB

  convert_kernel<<<dim3(N / 64, C / 64, B), dim3(256), 0, stream>>>(x, xf, xfT);
  gram_soft_av  <<<dim3(256),               dim3(512), 0, stream>>>(xf, xfT, beta, out);
}